// Round 1
// baseline (4486.527 us; speedup 1.0000x reference)
//
#include <hip/hip_runtime.h>
#include <math.h>

#define VOCABN 32000
#define EMBN 512
#define HIDN 512
#define BN 64
#define TSTEPS 33   // MAX_LEN + 1
#define OUTROWS (TSTEPS * VOCABN)

typedef float f4 __attribute__((ext_vector_type(4)));

// ---------------- init: h = enc_h[0], c = enc_c[0], tok = SOS ----------------
__global__ __launch_bounds__(256) void k_init(const float* __restrict__ eh,
                                              const float* __restrict__ ec,
                                              float* __restrict__ h,
                                              float* __restrict__ c,
                                              int* __restrict__ tok) {
    int i = blockIdx.x * 256 + threadIdx.x;
    if (i < BN * HIDN) { h[i] = eh[i]; c[i] = ec[i]; }
    if (i < BN) tok[i] = 1; // SOS
}

// ---------------- K1a: partial gates GEMM ----------------
// gates[b][j] = dot(xh_b[0:1024], Wcat[j][0:1024]); split K into 4 slices of 256.
// part layout: part[(ks*64 + b)*2048 + j]
// grid = 128 blocks: jt = bid&31 (j0=jt*64), ks = bid>>5 (k0=ks*256)
__global__ __launch_bounds__(256) void k_gates(const float* __restrict__ W_ih,
                                               const float* __restrict__ W_hh,
                                               const float* __restrict__ emb,
                                               const float* __restrict__ h,
                                               const int* __restrict__ tok,
                                               float* __restrict__ part) {
    __shared__ float w_s[64][68]; // rows: j-tile, padded pitch 68 (272B, 16B aligned)
    __shared__ float x_s[64][68]; // rows: b
    const int tid = threadIdx.x;
    const int j0 = (blockIdx.x & 31) * 64;
    const int ks = blockIdx.x >> 5;
    const int k0 = ks * 256;
    const int tx = tid & 15;   // b-quad
    const int ty = tid >> 4;   // j-quad
    const int r  = tid >> 2;        // staging row 0..63
    const int cq = (tid & 3) * 16;  // staging col offset

    float acc[4][4]; // acc[bb][jj]
    #pragma unroll
    for (int i = 0; i < 4; ++i)
        #pragma unroll
        for (int j = 0; j < 4; ++j) acc[i][j] = 0.f;

    for (int kk = 0; kk < 256; kk += 64) {
        const int k = k0 + kk; // chunk start in [0,1024), never straddles 512
        __syncthreads();
        // stage W rows (concat of W_ih | W_hh along k)
        {
            const float* src = (k < 512) ? (W_ih + (size_t)(j0 + r) * 512 + k + cq)
                                         : (W_hh + (size_t)(j0 + r) * 512 + (k - 512) + cq);
            const f4* s4 = (const f4*)src;
            f4* d4 = (f4*)&w_s[r][cq];
            d4[0] = s4[0]; d4[1] = s4[1]; d4[2] = s4[2]; d4[3] = s4[3];
        }
        // stage xh rows (concat of emb[tok[b]] | h[b] along k)
        {
            const float* src = (k < 512) ? (emb + (size_t)tok[r] * 512 + k + cq)
                                         : (h + (size_t)r * 512 + (k - 512) + cq);
            const f4* s4 = (const f4*)src;
            f4* d4 = (f4*)&x_s[r][cq];
            d4[0] = s4[0]; d4[1] = s4[1]; d4[2] = s4[2]; d4[3] = s4[3];
        }
        __syncthreads();
        #pragma unroll 4
        for (int c4 = 0; c4 < 64; c4 += 4) {
            f4 wv[4], xv[4];
            #pragma unroll
            for (int jj = 0; jj < 4; ++jj) wv[jj] = *(const f4*)&w_s[ty * 4 + jj][c4];
            #pragma unroll
            for (int bb = 0; bb < 4; ++bb) xv[bb] = *(const f4*)&x_s[tx * 4 + bb][c4];
            #pragma unroll
            for (int e = 0; e < 4; ++e)
                #pragma unroll
                for (int bb = 0; bb < 4; ++bb)
                    #pragma unroll
                    for (int jj = 0; jj < 4; ++jj)
                        acc[bb][jj] += xv[bb][e] * wv[jj][e];
        }
    }
    #pragma unroll
    for (int bb = 0; bb < 4; ++bb) {
        const int b = tx * 4 + bb;
        f4 v = { acc[bb][0], acc[bb][1], acc[bb][2], acc[bb][3] };
        *(f4*)&part[((size_t)(ks * 64 + b)) * 2048 + j0 + ty * 4] = v;
    }
}

__device__ __forceinline__ float sigf(float x) { return 1.f / (1.f + expf(-x)); }

// ---------------- K1b: reduce partials + bias, LSTM cell update ----------------
// grid = 128 blocks * 256 threads = 32768 = B*H elements
__global__ __launch_bounds__(256) void k_cell(const float* __restrict__ part,
                                              const float* __restrict__ b_ih,
                                              const float* __restrict__ b_hh,
                                              float* __restrict__ h,
                                              float* __restrict__ c) {
    const int e = blockIdx.x * 256 + threadIdx.x; // b*512+u
    const int b = e >> 9, u = e & 511;
    float g[4];
    #pragma unroll
    for (int gi = 0; gi < 4; ++gi) {
        const int j = gi * 512 + u;
        float s = b_ih[j] + b_hh[j];
        #pragma unroll
        for (int ks = 0; ks < 4; ++ks) s += part[((size_t)(ks * 64 + b)) * 2048 + j];
        g[gi] = s;
    }
    const float ig = sigf(g[0]);
    const float fg = sigf(g[1]);
    const float gg = tanhf(g[2]);
    const float og = sigf(g[3]);
    const float cn = fg * c[e] + ig * gg;
    const float hn = og * tanhf(cn);
    c[e] = cn;
    h[e] = hn;
}

// ---------------- K2: logits GEMM, writes raw logits (+bias) into d_out row t --------
// logits[b][v] = dot(h_b, fc_w[v]) + fc_b[v]
// grid = 500 blocks, v0 = bid*64; out element: outrow[b*OUTROWS + v]
__global__ __launch_bounds__(256) void k_logits(const float* __restrict__ fc_w,
                                                const float* __restrict__ fc_b,
                                                const float* __restrict__ h,
                                                float* __restrict__ outrow) {
    __shared__ float w_s[64][68]; // rows: v
    __shared__ float h_s[64][68]; // rows: b
    const int tid = threadIdx.x;
    const int v0 = blockIdx.x * 64;
    const int tx = tid & 15;  // v-quad
    const int ty = tid >> 4;  // b-quad
    const int r  = tid >> 2;
    const int cq = (tid & 3) * 16;

    float acc[4][4]; // acc[bb][vv]
    #pragma unroll
    for (int i = 0; i < 4; ++i)
        #pragma unroll
        for (int j = 0; j < 4; ++j) acc[i][j] = 0.f;

    for (int k = 0; k < 512; k += 64) {
        __syncthreads();
        {
            const f4* s4 = (const f4*)(fc_w + (size_t)(v0 + r) * 512 + k + cq);
            f4* d4 = (f4*)&w_s[r][cq];
            d4[0] = s4[0]; d4[1] = s4[1]; d4[2] = s4[2]; d4[3] = s4[3];
        }
        {
            const f4* s4 = (const f4*)(h + (size_t)r * 512 + k + cq);
            f4* d4 = (f4*)&h_s[r][cq];
            d4[0] = s4[0]; d4[1] = s4[1]; d4[2] = s4[2]; d4[3] = s4[3];
        }
        __syncthreads();
        #pragma unroll 4
        for (int c4 = 0; c4 < 64; c4 += 4) {
            f4 wv[4], hv[4];
            #pragma unroll
            for (int vv = 0; vv < 4; ++vv) wv[vv] = *(const f4*)&w_s[tx * 4 + vv][c4];
            #pragma unroll
            for (int bb = 0; bb < 4; ++bb) hv[bb] = *(const f4*)&h_s[ty * 4 + bb][c4];
            #pragma unroll
            for (int e = 0; e < 4; ++e)
                #pragma unroll
                for (int bb = 0; bb < 4; ++bb)
                    #pragma unroll
                    for (int vv = 0; vv < 4; ++vv)
                        acc[bb][vv] += hv[bb][e] * wv[vv][e];
        }
    }
    const f4 bias4 = *(const f4*)&fc_b[v0 + tx * 4];
    #pragma unroll
    for (int bb = 0; bb < 4; ++bb) {
        const int b = ty * 4 + bb;
        f4 val = { acc[bb][0] + bias4[0], acc[bb][1] + bias4[1],
                   acc[bb][2] + bias4[2], acc[bb][3] + bias4[3] };
        *(f4*)&outrow[(size_t)b * OUTROWS + v0 + tx * 4] = val;
    }
}

// ---------------- K3: per-row log-softmax (in place) + argmax -> tok ----------------
// grid = 64 blocks (one per batch row)
__global__ __launch_bounds__(256) void k_softmax(float* __restrict__ outrow,
                                                 int* __restrict__ tok) {
    const int b = blockIdx.x, tid = threadIdx.x;
    float* row = outrow + (size_t)b * OUTROWS;
    __shared__ float sm[256];
    __shared__ int si[256];
    __shared__ float ss[256];

    // pass 1: max + argmax (first-max tie-break)
    float m = -1e30f; int mi = 0;
    for (int v = tid; v < VOCABN; v += 256) {
        float x = row[v];
        if (x > m) { m = x; mi = v; }
    }
    sm[tid] = m; si[tid] = mi;
    __syncthreads();
    for (int s = 128; s; s >>= 1) {
        if (tid < s) {
            float xo = sm[tid + s]; int io = si[tid + s];
            if (xo > sm[tid] || (xo == sm[tid] && io < si[tid])) { sm[tid] = xo; si[tid] = io; }
        }
        __syncthreads();
    }
    const float M = sm[0];

    // pass 2: sum of exp (deterministic fixed-order tree)
    float sum = 0.f;
    for (int v = tid; v < VOCABN; v += 256) sum += expf(row[v] - M);
    ss[tid] = sum;
    __syncthreads();
    for (int s = 128; s; s >>= 1) {
        if (tid < s) ss[tid] += ss[tid + s];
        __syncthreads();
    }
    const float L = M + logf(ss[0]);
    if (tid == 0) tok[b] = si[0];

    // pass 3: logp = logit - logsumexp, in place
    for (int v = tid; v < VOCABN; v += 256) row[v] = row[v] - L;
}

// ---------------- final: decoder_hidden = h ----------------
__global__ __launch_bounds__(256) void k_copyh(const float* __restrict__ h,
                                               float* __restrict__ dst) {
    int i = blockIdx.x * 256 + threadIdx.x;
    if (i < BN * HIDN) dst[i] = h[i];
}

extern "C" void kernel_launch(void* const* d_in, const int* in_sizes, int n_in,
                              void* d_out, int out_size, void* d_ws, size_t ws_size,
                              hipStream_t stream) {
    const float* enc_h = (const float*)d_in[0];
    const float* enc_c = (const float*)d_in[1];
    const float* emb   = (const float*)d_in[2];
    const float* W_ih  = (const float*)d_in[3];
    const float* W_hh  = (const float*)d_in[4];
    const float* b_ih  = (const float*)d_in[5];
    const float* b_hh  = (const float*)d_in[6];
    const float* fc_w  = (const float*)d_in[7];
    const float* fc_b  = (const float*)d_in[8];
    float* out = (float*)d_out;

    float* ws   = (float*)d_ws;
    float* h    = ws;              // 32768
    float* c    = h + 32768;       // 32768
    float* part = c + 32768;       // 4*64*2048 = 524288
    int*   tok  = (int*)(part + 524288);

    k_init<<<128, 256, 0, stream>>>(enc_h, enc_c, h, c, tok);
    for (int t = 0; t < TSTEPS; ++t) {
        k_gates<<<128, 256, 0, stream>>>(W_ih, W_hh, emb, h, tok, part);
        k_cell<<<128, 256, 0, stream>>>(part, b_ih, b_hh, h, c);
        float* outrow = out + (size_t)t * VOCABN;
        k_logits<<<500, 256, 0, stream>>>(fc_w, fc_b, h, outrow);
        k_softmax<<<64, 256, 0, stream>>>(outrow, tok);
    }
    k_copyh<<<128, 256, 0, stream>>>(h, out + (size_t)BN * OUTROWS);
}

// Round 2
// 2559.662 us; speedup vs baseline: 1.7528x; 1.7528x over previous
//
#include <hip/hip_runtime.h>
#include <math.h>

#define VOCABN 32000
#define EMBN 512
#define HIDN 512
#define BN 64
#define TSTEPS 33   // MAX_LEN + 1
#define OUTROWS (TSTEPS * VOCABN)

typedef float f4 __attribute__((ext_vector_type(4)));

// ---------------- init: h = enc_h[0], c = enc_c[0], tok = SOS ----------------
__global__ __launch_bounds__(256) void k_init(const float* __restrict__ eh,
                                              const float* __restrict__ ec,
                                              float* __restrict__ h,
                                              float* __restrict__ c,
                                              int* __restrict__ tok) {
    int i = blockIdx.x * 256 + threadIdx.x;
    if (i < BN * HIDN) { h[i] = eh[i]; c[i] = ec[i]; }
    if (i < BN) tok[i] = 1; // SOS
}

// ---------------- K1a: partial gates GEMM ----------------
// gates[b][j] = dot(xh_b[0:1024], Wcat[j][0:1024]); K split into 4 slices of 256.
// part layout: part[(ks*64 + b)*2048 + j]
// grid = 128 blocks: jt = bid&31 (j0=jt*64), ks = bid>>5 (k0=ks*256)
// Fragment mapping (bank-conflict-free): j = j0 + 16*jj + tx, b = 16*bb + ty
__global__ __launch_bounds__(256) void k_gates(const float* __restrict__ W_ih,
                                               const float* __restrict__ W_hh,
                                               const float* __restrict__ emb,
                                               const float* __restrict__ h,
                                               const int* __restrict__ tok,
                                               float* __restrict__ part) {
    __shared__ float w_s[64][68]; // rows: j-tile; pitch 68 => 4-bank row stride
    __shared__ float x_s[64][68]; // rows: b
    const int tid = threadIdx.x;
    const int j0 = (blockIdx.x & 31) * 64;
    const int ks = blockIdx.x >> 5;
    const int k0 = ks * 256;
    const int tx = tid & 15;   // j fine index
    const int ty = tid >> 4;   // b fine index (0..15)
    const int r  = tid >> 2;        // staging row 0..63
    const int cq = (tid & 3) * 16;  // staging col offset

    float acc[4][4]; // acc[bb][jj]
    #pragma unroll
    for (int i = 0; i < 4; ++i)
        #pragma unroll
        for (int j = 0; j < 4; ++j) acc[i][j] = 0.f;

    for (int kk = 0; kk < 256; kk += 64) {
        const int k = k0 + kk; // chunk start in [0,1024), never straddles 512
        __syncthreads();
        // stage W rows (concat of W_ih | W_hh along k)
        {
            const float* src = (k < 512) ? (W_ih + (size_t)(j0 + r) * 512 + k + cq)
                                         : (W_hh + (size_t)(j0 + r) * 512 + (k - 512) + cq);
            const f4* s4 = (const f4*)src;
            f4* d4 = (f4*)&w_s[r][cq];
            d4[0] = s4[0]; d4[1] = s4[1]; d4[2] = s4[2]; d4[3] = s4[3];
        }
        // stage xh rows (concat of emb[tok[b]] | h[b] along k)
        {
            const float* src = (k < 512) ? (emb + (size_t)tok[r] * 512 + k + cq)
                                         : (h + (size_t)r * 512 + (k - 512) + cq);
            const f4* s4 = (const f4*)src;
            f4* d4 = (f4*)&x_s[r][cq];
            d4[0] = s4[0]; d4[1] = s4[1]; d4[2] = s4[2]; d4[3] = s4[3];
        }
        __syncthreads();
        #pragma unroll 4
        for (int c4 = 0; c4 < 64; c4 += 4) {
            f4 wv[4], xv[4];
            #pragma unroll
            for (int jj = 0; jj < 4; ++jj) wv[jj] = *(const f4*)&w_s[16 * jj + tx][c4];
            #pragma unroll
            for (int bb = 0; bb < 4; ++bb) xv[bb] = *(const f4*)&x_s[16 * bb + ty][c4];
            #pragma unroll
            for (int e = 0; e < 4; ++e)
                #pragma unroll
                for (int bb = 0; bb < 4; ++bb)
                    #pragma unroll
                    for (int jj = 0; jj < 4; ++jj)
                        acc[bb][jj] += xv[bb][e] * wv[jj][e];
        }
    }
    #pragma unroll
    for (int bb = 0; bb < 4; ++bb) {
        const int b = 16 * bb + ty;
        #pragma unroll
        for (int jj = 0; jj < 4; ++jj)
            part[((size_t)(ks * 64 + b)) * 2048 + j0 + 16 * jj + tx] = acc[bb][jj];
    }
}

__device__ __forceinline__ float sigf(float x) { return 1.f / (1.f + expf(-x)); }

// ---------------- K1b: reduce partials + bias, LSTM cell update ----------------
__global__ __launch_bounds__(256) void k_cell(const float* __restrict__ part,
                                              const float* __restrict__ b_ih,
                                              const float* __restrict__ b_hh,
                                              float* __restrict__ h,
                                              float* __restrict__ c) {
    const int e = blockIdx.x * 256 + threadIdx.x; // b*512+u
    const int b = e >> 9, u = e & 511;
    float g[4];
    #pragma unroll
    for (int gi = 0; gi < 4; ++gi) {
        const int j = gi * 512 + u;
        float s = b_ih[j] + b_hh[j];
        #pragma unroll
        for (int ks = 0; ks < 4; ++ks) s += part[((size_t)(ks * 64 + b)) * 2048 + j];
        g[gi] = s;
    }
    const float ig = sigf(g[0]);
    const float fg = sigf(g[1]);
    const float gg = tanhf(g[2]);
    const float og = sigf(g[3]);
    const float cn = fg * c[e] + ig * gg;
    const float hn = og * tanhf(cn);
    c[e] = cn;
    h[e] = hn;
}

// ---------------- K2: logits GEMM, writes raw logits (+bias) into d_out row t --------
// grid = 500 blocks, v0 = bid*64
// Fragment mapping (bank-conflict-free): v = v0 + 16*vv + tx, b = 16*bb + ty
__global__ __launch_bounds__(256) void k_logits(const float* __restrict__ fc_w,
                                                const float* __restrict__ fc_b,
                                                const float* __restrict__ h,
                                                float* __restrict__ outrow) {
    __shared__ float w_s[64][68]; // rows: v
    __shared__ float h_s[64][68]; // rows: b
    const int tid = threadIdx.x;
    const int v0 = blockIdx.x * 64;
    const int tx = tid & 15;  // v fine index
    const int ty = tid >> 4;  // b fine index (0..15)
    const int r  = tid >> 2;
    const int cq = (tid & 3) * 16;

    float acc[4][4]; // acc[bb][vv]
    #pragma unroll
    for (int i = 0; i < 4; ++i)
        #pragma unroll
        for (int j = 0; j < 4; ++j) acc[i][j] = 0.f;

    for (int k = 0; k < 512; k += 64) {
        __syncthreads();
        {
            const f4* s4 = (const f4*)(fc_w + (size_t)(v0 + r) * 512 + k + cq);
            f4* d4 = (f4*)&w_s[r][cq];
            d4[0] = s4[0]; d4[1] = s4[1]; d4[2] = s4[2]; d4[3] = s4[3];
        }
        {
            const f4* s4 = (const f4*)(h + (size_t)r * 512 + k + cq);
            f4* d4 = (f4*)&h_s[r][cq];
            d4[0] = s4[0]; d4[1] = s4[1]; d4[2] = s4[2]; d4[3] = s4[3];
        }
        __syncthreads();
        #pragma unroll 4
        for (int c4 = 0; c4 < 64; c4 += 4) {
            f4 wv[4], hv[4];
            #pragma unroll
            for (int vv = 0; vv < 4; ++vv) wv[vv] = *(const f4*)&w_s[16 * vv + tx][c4];
            #pragma unroll
            for (int bb = 0; bb < 4; ++bb) hv[bb] = *(const f4*)&h_s[16 * bb + ty][c4];
            #pragma unroll
            for (int e = 0; e < 4; ++e)
                #pragma unroll
                for (int bb = 0; bb < 4; ++bb)
                    #pragma unroll
                    for (int vv = 0; vv < 4; ++vv)
                        acc[bb][vv] += hv[bb][e] * wv[vv][e];
        }
    }
    float bias[4];
    #pragma unroll
    for (int vv = 0; vv < 4; ++vv) bias[vv] = fc_b[v0 + 16 * vv + tx];
    #pragma unroll
    for (int bb = 0; bb < 4; ++bb) {
        const int b = 16 * bb + ty;
        #pragma unroll
        for (int vv = 0; vv < 4; ++vv)
            outrow[(size_t)b * OUTROWS + v0 + 16 * vv + tx] = acc[bb][vv] + bias[vv];
    }
}

// ---------------- K3: per-row log-softmax (in place) + argmax -> tok ----------------
// grid = 64 blocks (one per batch row), 1024 threads
__global__ __launch_bounds__(1024) void k_softmax(float* __restrict__ outrow,
                                                  int* __restrict__ tok) {
    const int b = blockIdx.x, tid = threadIdx.x;
    float* row = outrow + (size_t)b * OUTROWS;
    __shared__ float sm[1024];
    __shared__ int si[1024];

    // pass 1: max + argmax (first-max tie-break), exact fp32 compares
    float m = -1e30f; int mi = 0;
    for (int v = tid; v < VOCABN; v += 1024) {
        float x = row[v];
        if (x > m) { m = x; mi = v; }
    }
    sm[tid] = m; si[tid] = mi;
    __syncthreads();
    for (int s = 512; s; s >>= 1) {
        if (tid < s) {
            float xo = sm[tid + s]; int io = si[tid + s];
            if (xo > sm[tid] || (xo == sm[tid] && io < si[tid])) { sm[tid] = xo; si[tid] = io; }
        }
        __syncthreads();
    }
    const float M = sm[0];
    const int ami = si[0];
    __syncthreads();

    // pass 2: sum of exp (deterministic fixed-order tree)
    float sum = 0.f;
    for (int v = tid; v < VOCABN; v += 1024) sum += __expf(row[v] - M);
    sm[tid] = sum;
    __syncthreads();
    for (int s = 512; s; s >>= 1) {
        if (tid < s) sm[tid] += sm[tid + s];
        __syncthreads();
    }
    const float L = M + logf(sm[0]);
    if (tid == 0) tok[b] = ami;

    // pass 3: logp = logit - logsumexp, in place
    for (int v = tid; v < VOCABN; v += 1024) row[v] = row[v] - L;
}

// ---------------- final: decoder_hidden = h ----------------
__global__ __launch_bounds__(256) void k_copyh(const float* __restrict__ h,
                                               float* __restrict__ dst) {
    int i = blockIdx.x * 256 + threadIdx.x;
    if (i < BN * HIDN) dst[i] = h[i];
}

extern "C" void kernel_launch(void* const* d_in, const int* in_sizes, int n_in,
                              void* d_out, int out_size, void* d_ws, size_t ws_size,
                              hipStream_t stream) {
    const float* enc_h = (const float*)d_in[0];
    const float* enc_c = (const float*)d_in[1];
    const float* emb   = (const float*)d_in[2];
    const float* W_ih  = (const float*)d_in[3];
    const float* W_hh  = (const float*)d_in[4];
    const float* b_ih  = (const float*)d_in[5];
    const float* b_hh  = (const float*)d_in[6];
    const float* fc_w  = (const float*)d_in[7];
    const float* fc_b  = (const float*)d_in[8];
    float* out = (float*)d_out;

    float* ws   = (float*)d_ws;
    float* h    = ws;              // 32768
    float* c    = h + 32768;       // 32768
    float* part = c + 32768;       // 4*64*2048 = 524288
    int*   tok  = (int*)(part + 524288);

    k_init<<<128, 256, 0, stream>>>(enc_h, enc_c, h, c, tok);
    for (int t = 0; t < TSTEPS; ++t) {
        k_gates<<<128, 256, 0, stream>>>(W_ih, W_hh, emb, h, tok, part);
        k_cell<<<128, 256, 0, stream>>>(part, b_ih, b_hh, h, c);
        float* outrow = out + (size_t)t * VOCABN;
        k_logits<<<500, 256, 0, stream>>>(fc_w, fc_b, h, outrow);
        k_softmax<<<64, 1024, 0, stream>>>(outrow, tok);
    }
    k_copyh<<<128, 256, 0, stream>>>(h, out + (size_t)BN * OUTROWS);
}